// Round 1
// baseline (113.642 us; speedup 1.0000x reference)
//
#include <hip/hip_runtime.h>

#define N 8192
#define D 128
#define MARGIN 0.5f

typedef __bf16 bf16x8 __attribute__((ext_vector_type(8)));
typedef float f32x4 __attribute__((ext_vector_type(4)));

__device__ __forceinline__ unsigned short f2bf_rne(float f) {
  unsigned u = __float_as_uint(f);
  u += 0x7FFFu + ((u >> 16) & 1u);   // round-to-nearest-even (inputs are finite/normal)
  return (unsigned short)(u >> 16);
}

// ---------------- K0: init workspace accumulators ----------------
__global__ void k_init(unsigned* __restrict__ posw, unsigned* __restrict__ negw,
                       unsigned* __restrict__ hist, float* __restrict__ acc) {
  int i = blockIdx.x * blockDim.x + threadIdx.x;
  if (i < N) { posw[i] = 0u; negw[i] = 0x7F800000u; }  // pos d2 max init 0, neg d2 min init +inf
  if (i < 8) hist[i] = 0u;
  if (i == 0) { acc[0] = 0.f; acc[1] = 0.f; }
}

// ---------------- K1: fp32 -> bf16 + row squared norms ----------------
// one wave per row; thread t handles 2 elements
__global__ void k_convert(const float* __restrict__ x, unsigned short* __restrict__ xb,
                          float* __restrict__ sq) {
  const int row = blockIdx.x;
  const int t = threadIdx.x;  // 0..63
  const float2 v = ((const float2*)x)[row * 64 + t];
  ushort2 o;
  o.x = f2bf_rne(v.x);
  o.y = f2bf_rne(v.y);
  ((ushort2*)xb)[row * 64 + t] = o;
  float s = v.x * v.x + v.y * v.y;  // norms in fp32 (reference parity)
#pragma unroll
  for (int off = 32; off; off >>= 1) s += __shfl_xor(s, off, 64);
  if (t == 0) sq[row] = s;
}

// ---------------- K1b: label histogram (validity) ----------------
__global__ void k_hist(const int* __restrict__ lab, unsigned* __restrict__ hist) {
  __shared__ unsigned h[8];
  const int t = threadIdx.x;
  if (t < 8) h[t] = 0u;
  __syncthreads();
  const int i = blockIdx.x * blockDim.x + t;
  if (i < N) atomicAdd(&h[lab[i] & 7], 1u);
  __syncthreads();
  if (t < 8) atomicAdd(&hist[t], h[t]);
}

// ---------------- K2: fused GEMM + hardest-pos/neg mining ----------------
// block = 256 thr (4 waves). Each block: 128 i-rows (wave: 2 subtiles of 16),
// j-range = 1024 rows (blockIdx.y of 8), staged in 64-row LDS tiles.
// A fragments live in registers for the whole j loop.
__global__ __launch_bounds__(256, 2) void k_mine(
    const unsigned short* __restrict__ xb, const float* __restrict__ sq,
    const int* __restrict__ lab, unsigned* __restrict__ posw, unsigned* __restrict__ negw) {
  // padded row: 128 + 8 bf16 -> 272 B/row -> bank advance 4, 2-way (free)
  __shared__ __align__(16) unsigned short lds_b[64 * 136];
  __shared__ float lds_sq[64];
  __shared__ int lds_lab[64];

  const int t = threadIdx.x;
  const int w = t >> 6;
  const int lane = t & 63;
  const int col = lane & 15;   // MFMA n / fragment row selector
  const int quad = lane >> 4;  // MFMA k-group / C row group
  const int i0 = blockIdx.x * 128 + w * 32;

  // A fragments: 2 i-subtiles x 4 k-steps, 16B per lane each
  bf16x8 a[2][4];
#pragma unroll
  for (int is = 0; is < 2; ++is) {
    const unsigned short* arow = xb + (size_t)(i0 + is * 16 + col) * D + quad * 8;
#pragma unroll
    for (int k = 0; k < 4; ++k) a[is][k] = *(const bf16x8*)(arow + k * 32);
  }

  // per-lane row metadata (C layout: row = quad*4 + r)
  float sqi[2][4];
  int labi[2][4], ig[2][4];
#pragma unroll
  for (int is = 0; is < 2; ++is)
#pragma unroll
    for (int r = 0; r < 4; ++r) {
      const int i = i0 + is * 16 + quad * 4 + r;
      ig[is][r] = i;
      sqi[is][r] = sq[i];
      labi[is][r] = lab[i];
    }

  float pos[2][4], neg[2][4];
#pragma unroll
  for (int is = 0; is < 2; ++is)
#pragma unroll
    for (int r = 0; r < 4; ++r) { pos[is][r] = -1.0f; neg[is][r] = 3.402823466e+38f; }

  const int jbase = blockIdx.y * 1024;
  for (int jt = 0; jt < 16; ++jt) {
    const int j0 = jbase + jt * 64;
    __syncthreads();  // protect LDS reuse
#pragma unroll
    for (int p = 0; p < 4; ++p) {  // stage 64 rows x 128 bf16, coalesced 16B/thread
      const int row = p * 16 + (t >> 4);
      const int cg = t & 15;
      const uint4 v = *(const uint4*)(xb + (size_t)(j0 + row) * D + cg * 8);
      *(uint4*)(lds_b + row * 136 + cg * 8) = v;
    }
    if (t < 64) {
      lds_sq[t] = sq[j0 + t];
      lds_lab[t] = lab[j0 + t];
    }
    __syncthreads();

#pragma unroll
    for (int s = 0; s < 4; ++s) {  // 4 j-subtiles of 16
      f32x4 acc0 = {0.f, 0.f, 0.f, 0.f}, acc1 = {0.f, 0.f, 0.f, 0.f};
#pragma unroll
      for (int k = 0; k < 4; ++k) {
        const bf16x8 b = *(const bf16x8*)(lds_b + (s * 16 + col) * 136 + k * 32 + quad * 8);
        acc0 = __builtin_amdgcn_mfma_f32_16x16x32_bf16(a[0][k], b, acc0, 0, 0, 0);
        acc1 = __builtin_amdgcn_mfma_f32_16x16x32_bf16(a[1][k], b, acc1, 0, 0, 0);
      }
      const int jc = s * 16 + col;
      const float sqj = lds_sq[jc];
      const int labj = lds_lab[jc];
      const int jg = j0 + jc;
#pragma unroll
      for (int r = 0; r < 4; ++r) {
        const float d20 = sqi[0][r] + sqj - 2.f * acc0[r];
        const float d21 = sqi[1][r] + sqj - 2.f * acc1[r];
        if (labi[0][r] == labj) {
          if (ig[0][r] != jg) pos[0][r] = fmaxf(pos[0][r], d20);
        } else {
          neg[0][r] = fminf(neg[0][r], d20);
        }
        if (labi[1][r] == labj) {
          if (ig[1][r] != jg) pos[1][r] = fmaxf(pos[1][r], d21);
        } else {
          neg[1][r] = fminf(neg[1][r], d21);
        }
      }
    }
  }

  // reduce across the 16 lanes (cols) sharing each row, then combine globally.
  // d2 >= 0 after clamp -> float bits order as uint.
#pragma unroll
  for (int is = 0; is < 2; ++is)
#pragma unroll
    for (int r = 0; r < 4; ++r) {
      float p = pos[is][r], n = neg[is][r];
#pragma unroll
      for (int off = 1; off < 16; off <<= 1) {
        p = fmaxf(p, __shfl_xor(p, off, 64));
        n = fminf(n, __shfl_xor(n, off, 64));
      }
      if (col == 0) {
        atomicMax(posw + ig[is][r], __float_as_uint(fmaxf(p, 0.f)));
        atomicMin(negw + ig[is][r], __float_as_uint(fmaxf(n, 0.f)));
      }
    }
}

// ---------------- K3: per-row loss + reduction ----------------
__global__ void k_rowloss(const unsigned* __restrict__ posw, const unsigned* __restrict__ negw,
                          const int* __restrict__ lab, const unsigned* __restrict__ hist,
                          float* __restrict__ acc) {
  __shared__ float ls[4], cs[4];
  const int i = blockIdx.x * 256 + threadIdx.x;
  const float pd2 = __uint_as_float(posw[i]);
  const float nd2 = __uint_as_float(negw[i]);
  const unsigned cnt = hist[lab[i] & 7];
  const bool valid = (cnt >= 2u) && (cnt < (unsigned)N);
  float loss = 0.f, c = 0.f;
  if (valid) {
    const float pd = sqrtf(fmaxf(pd2, 0.f));
    const float nd = sqrtf(fmaxf(nd2, 0.f));
    loss = fmaxf(pd - nd + MARGIN, 0.f);
    c = 1.f;
  }
#pragma unroll
  for (int off = 1; off < 64; off <<= 1) {
    loss += __shfl_xor(loss, off, 64);
    c += __shfl_xor(c, off, 64);
  }
  const int wv = threadIdx.x >> 6;
  if ((threadIdx.x & 63) == 0) { ls[wv] = loss; cs[wv] = c; }
  __syncthreads();
  if (threadIdx.x == 0) {
    atomicAdd(acc + 0, ls[0] + ls[1] + ls[2] + ls[3]);
    atomicAdd(acc + 1, cs[0] + cs[1] + cs[2] + cs[3]);
  }
}

// ---------------- K4: finalize ----------------
__global__ void k_final(const float* __restrict__ acc, float* __restrict__ out) {
  out[0] = acc[0] / fmaxf(acc[1], 1.f);
}

extern "C" void kernel_launch(void* const* d_in, const int* in_sizes, int n_in,
                              void* d_out, int out_size, void* d_ws, size_t ws_size,
                              hipStream_t stream) {
  const float* x = (const float*)d_in[0];
  const int* lab = (const int*)d_in[1];
  char* ws = (char*)d_ws;
  unsigned short* xb = (unsigned short*)ws;                       // 2 MB bf16 copy
  float* sq = (float*)(ws + (size_t)N * D * 2);                   // 32 KB
  unsigned* posw = (unsigned*)((char*)sq + (size_t)N * 4);        // 32 KB
  unsigned* negw = posw + N;                                      // 32 KB
  unsigned* hist = negw + N;                                      // 32 B
  float* acc = (float*)(hist + 8);                                // 8 B
  float* out = (float*)d_out;

  hipLaunchKernelGGL(k_init, dim3(32), dim3(256), 0, stream, posw, negw, hist, acc);
  hipLaunchKernelGGL(k_convert, dim3(N), dim3(64), 0, stream, x, xb, sq);
  hipLaunchKernelGGL(k_hist, dim3(16), dim3(512), 0, stream, lab, hist);
  hipLaunchKernelGGL(k_mine, dim3(64, 8), dim3(256), 0, stream, xb, sq, lab, posw, negw);
  hipLaunchKernelGGL(k_rowloss, dim3(32), dim3(256), 0, stream, posw, negw, lab, hist, acc);
  hipLaunchKernelGGL(k_final, dim3(1), dim3(1), 0, stream, acc, out);
}

// Round 2
// 107.840 us; speedup vs baseline: 1.0538x; 1.0538x over previous
//
#include <hip/hip_runtime.h>

#define N 8192
#define D 128
#define MARGIN 0.5f
#define FLT_BIG 3.402823466e+38f

typedef __bf16 bf16x8 __attribute__((ext_vector_type(8)));
typedef float f32x4 __attribute__((ext_vector_type(4)));

__device__ __forceinline__ unsigned short f2bf_rne(float f) {
  unsigned u = __float_as_uint(f);
  u += 0x7FFFu + ((u >> 16) & 1u);  // round-to-nearest-even (inputs finite)
  return (unsigned short)(u >> 16);
}

// ---------------- K1: fp32->bf16 + row norms + all init (+ hist in block 0) ----
// grid 1024 x 256: 8 rows/block, 32 threads (one float4 each) per row.
__global__ void k_prep(const float* __restrict__ x, const int* __restrict__ lab,
                       unsigned short* __restrict__ xb, float* __restrict__ sq,
                       unsigned* __restrict__ posw, unsigned* __restrict__ negw,
                       unsigned* __restrict__ hist, float* __restrict__ acc,
                       unsigned* __restrict__ ticket) {
  const int t = threadIdx.x;
  const int row = blockIdx.x * 8 + (t >> 5);
  const int l32 = t & 31;
  const float4 v = ((const float4*)x)[row * 32 + l32];
  ushort4 o;
  o.x = f2bf_rne(v.x); o.y = f2bf_rne(v.y);
  o.z = f2bf_rne(v.z); o.w = f2bf_rne(v.w);
  ((ushort4*)xb)[row * 32 + l32] = o;
  float s = v.x * v.x + v.y * v.y + v.z * v.z + v.w * v.w;
#pragma unroll
  for (int off = 1; off < 32; off <<= 1) s += __shfl_xor(s, off, 64);
  if (l32 == 0) {
    sq[row] = s;
    posw[row] = 0u;           // max(d2) accumulator
    negw[row] = 0x7F800000u;  // min(d2) accumulator = +inf
  }

  if (blockIdx.x == 0) {  // label histogram, 256 threads read all 8192 labels
    __shared__ unsigned h[8];
    if (t < 8) h[t] = 0u;
    __syncthreads();
    unsigned long long cA = 0ull, cB = 0ull;  // 4x16-bit packed counters each
#pragma unroll
    for (int it = 0; it < 32; ++it) {
      const int l = lab[t + it * 256] & 7;
      if (l < 4) cA += 1ull << (l * 16);
      else       cB += 1ull << ((l - 4) * 16);
    }
#pragma unroll
    for (int off = 1; off < 64; off <<= 1) {
      cA += __shfl_xor(cA, off, 64);
      cB += __shfl_xor(cB, off, 64);
    }
    if ((t & 63) == 0) {
#pragma unroll
      for (int q = 0; q < 4; ++q) {
        atomicAdd(&h[q],     (unsigned)((cA >> (q * 16)) & 0xFFFFu));
        atomicAdd(&h[4 + q], (unsigned)((cB >> (q * 16)) & 0xFFFFu));
      }
    }
    __syncthreads();
    if (t < 8) hist[t] = h[t];
    if (t == 0) { acc[0] = 0.f; acc[1] = 0.f; ticket[0] = 0u; }
  }
}

// ---------------- K2: fused GEMM + hardest-pos/neg mining ----------------
// grid (64,16) x 256thr. Block: 128 i-rows x 512 j-rows; 8 LDS tiles of 64 j.
// XOR-swizzled B tile (chunk = cg ^ (row&7)) -> conflict-free b128 read/write.
__global__ __launch_bounds__(256, 4) void k_mine(
    const unsigned short* __restrict__ xb, const float* __restrict__ sq,
    const int* __restrict__ lab, unsigned* __restrict__ posw, unsigned* __restrict__ negw) {
  __shared__ __align__(16) unsigned short lds_b[64 * 128];
  __shared__ float lds_sq[64];
  __shared__ int lds_lab[64];

  const int t = threadIdx.x;
  const int w = t >> 6;
  const int lane = t & 63;
  const int col = lane & 15;   // MFMA m/n selector
  const int quad = lane >> 4;  // MFMA k-group / C row group
  const int iblk = blockIdx.x * 128;
  const int i0 = iblk + w * 32;

  // A fragments resident: 2 i-subtiles x 4 k-steps
  bf16x8 a[2][4];
#pragma unroll
  for (int is = 0; is < 2; ++is) {
    const unsigned short* arow = xb + (size_t)(i0 + is * 16 + col) * D + quad * 8;
#pragma unroll
    for (int k = 0; k < 4; ++k) a[is][k] = *(const bf16x8*)(arow + k * 32);
  }

  int labi[2][4];
#pragma unroll
  for (int is = 0; is < 2; ++is)
#pragma unroll
    for (int r = 0; r < 4; ++r) labi[is][r] = lab[i0 + is * 16 + quad * 4 + r];

  float pos[2][4], neg[2][4];
#pragma unroll
  for (int is = 0; is < 2; ++is)
#pragma unroll
    for (int r = 0; r < 4; ++r) { pos[is][r] = -FLT_BIG; neg[is][r] = FLT_BIG; }

  // swizzled read offsets (bytes): chunk (k*4+quad) stored at chunk^(col&7)
  const int cm = col & 7;
  int coff[4];
#pragma unroll
  for (int k = 0; k < 4; ++k) coff[k] = col * 256 + (((k * 4 + quad) ^ cm) * 16);

  const int jbase = blockIdx.y * 512;
  for (int jt = 0; jt < 8; ++jt) {
    const int j0 = jbase + jt * 64;
    __syncthreads();
#pragma unroll
    for (int p = 0; p < 4; ++p) {  // stage 64 rows x 256B, swizzled
      const int row = p * 16 + (t >> 4);
      const int cg = t & 15;
      const uint4 v = *(const uint4*)(xb + (size_t)(j0 + row) * D + cg * 8);
      *(uint4*)((char*)lds_b + row * 256 + ((cg ^ (row & 7)) * 16)) = v;
    }
    if (t < 64) { lds_sq[t] = sq[j0 + t]; lds_lab[t] = lab[j0 + t]; }
    __syncthreads();

    const bool diag = (j0 < iblk + 128) && (iblk < j0 + 64);

#pragma unroll
    for (int s = 0; s < 4; ++s) {
      f32x4 acc0 = {0.f, 0.f, 0.f, 0.f}, acc1 = {0.f, 0.f, 0.f, 0.f};
#pragma unroll
      for (int k = 0; k < 4; ++k) {
        const bf16x8 b = *(const bf16x8*)((const char*)lds_b + s * 4096 + coff[k]);
        acc0 = __builtin_amdgcn_mfma_f32_16x16x32_bf16(a[0][k], b, acc0, 0, 0, 0);
        acc1 = __builtin_amdgcn_mfma_f32_16x16x32_bf16(a[1][k], b, acc1, 0, 0, 0);
      }
      const int jc = s * 16 + col;
      const float sqj = lds_sq[jc];
      const int labj = lds_lab[jc];
      if (!diag) {
#pragma unroll
        for (int r = 0; r < 4; ++r) {
          const float m0 = fmaf(-2.f, acc0[r], sqj);
          const float m1 = fmaf(-2.f, acc1[r], sqj);
          const bool s0 = (labi[0][r] == labj);
          const bool s1 = (labi[1][r] == labj);
          pos[0][r] = fmaxf(pos[0][r], s0 ? m0 : -FLT_BIG);
          neg[0][r] = fminf(neg[0][r], s0 ? FLT_BIG : m0);
          pos[1][r] = fmaxf(pos[1][r], s1 ? m1 : -FLT_BIG);
          neg[1][r] = fminf(neg[1][r], s1 ? FLT_BIG : m1);
        }
      } else {
        const int jg = j0 + jc;
#pragma unroll
        for (int r = 0; r < 4; ++r) {
          const int ir = quad * 4 + r;
          const float m0 = fmaf(-2.f, acc0[r], sqj);
          const float m1 = fmaf(-2.f, acc1[r], sqj);
          const bool s0 = (labi[0][r] == labj) && (jg != i0 + ir);
          const bool s1 = (labi[1][r] == labj) && (jg != i0 + 16 + ir);
          pos[0][r] = fmaxf(pos[0][r], s0 ? m0 : -FLT_BIG);
          neg[0][r] = fminf(neg[0][r], (labi[0][r] == labj) ? FLT_BIG : m0);
          pos[1][r] = fmaxf(pos[1][r], s1 ? m1 : -FLT_BIG);
          neg[1][r] = fminf(neg[1][r], (labi[1][r] == labj) ? FLT_BIG : m1);
        }
      }
    }
  }

  // reduce the 16 cols sharing each i-row, add sq_i back, combine via atomics
#pragma unroll
  for (int is = 0; is < 2; ++is)
#pragma unroll
    for (int r = 0; r < 4; ++r) {
      float p = pos[is][r], n = neg[is][r];
#pragma unroll
      for (int off = 1; off < 16; off <<= 1) {
        p = fmaxf(p, __shfl_xor(p, off, 64));
        n = fminf(n, __shfl_xor(n, off, 64));
      }
      if (col == 0) {
        const int i = i0 + is * 16 + quad * 4 + r;
        const float sqi = sq[i];
        atomicMax(posw + i, __float_as_uint(fmaxf(sqi + p, 0.f)));
        atomicMin(negw + i, __float_as_uint(fmaxf(sqi + n, 0.f)));
      }
    }
}

// ---------------- K3: per-row loss + global reduce + finalize (ticketed) -----
__global__ void k_tail(const unsigned* __restrict__ posw, const unsigned* __restrict__ negw,
                       const int* __restrict__ lab, const unsigned* __restrict__ hist,
                       float* __restrict__ acc, unsigned* __restrict__ ticket,
                       float* __restrict__ out) {
  __shared__ float ls[4], cs[4];
  const int t = threadIdx.x;
  const int i = blockIdx.x * 256 + t;
  const float pd2 = __uint_as_float(posw[i]);
  const float nd2 = __uint_as_float(negw[i]);
  const unsigned cnt = hist[lab[i] & 7];
  const bool valid = (cnt >= 2u) && (cnt < (unsigned)N);
  float loss = 0.f, c = 0.f;
  if (valid) {
    loss = fmaxf(sqrtf(pd2) - sqrtf(fminf(nd2, FLT_BIG)) + MARGIN, 0.f);
    c = 1.f;
  }
#pragma unroll
  for (int off = 1; off < 64; off <<= 1) {
    loss += __shfl_xor(loss, off, 64);
    c += __shfl_xor(c, off, 64);
  }
  const int wv = t >> 6;
  if ((t & 63) == 0) { ls[wv] = loss; cs[wv] = c; }
  __syncthreads();
  if (t == 0) {
    atomicAdd(acc + 0, ls[0] + ls[1] + ls[2] + ls[3]);
    atomicAdd(acc + 1, cs[0] + cs[1] + cs[2] + cs[3]);
    __threadfence();
    const unsigned tk = atomicAdd(ticket, 1u);
    if (tk == 31u) {  // last block: all partials fenced-in; read via atomics (coherent)
      const float lsum = atomicAdd(acc + 0, 0.f);
      const float csum = atomicAdd(acc + 1, 0.f);
      out[0] = lsum / fmaxf(csum, 1.f);
    }
  }
}

extern "C" void kernel_launch(void* const* d_in, const int* in_sizes, int n_in,
                              void* d_out, int out_size, void* d_ws, size_t ws_size,
                              hipStream_t stream) {
  const float* x = (const float*)d_in[0];
  const int* lab = (const int*)d_in[1];
  char* ws = (char*)d_ws;
  unsigned short* xb = (unsigned short*)ws;                 // 2 MB bf16 copy
  float* sq = (float*)(ws + (size_t)N * D * 2);             // 32 KB
  unsigned* posw = (unsigned*)((char*)sq + (size_t)N * 4);  // 32 KB
  unsigned* negw = posw + N;                                // 32 KB
  unsigned* hist = negw + N;                                // 32 B
  unsigned* ticket = hist + 8;                              // 4 B
  float* acc = (float*)(ticket + 1);                        // 8 B
  float* out = (float*)d_out;

  hipLaunchKernelGGL(k_prep, dim3(1024), dim3(256), 0, stream, x, lab, xb, sq,
                     posw, negw, hist, acc, ticket);
  hipLaunchKernelGGL(k_mine, dim3(64, 16), dim3(256), 0, stream, xb, sq, lab, posw, negw);
  hipLaunchKernelGGL(k_tail, dim3(32), dim3(256), 0, stream, posw, negw, lab, hist,
                     acc, ticket, out);
}